// Round 6
// baseline (400.227 us; speedup 1.0000x reference)
//
#include <hip/hip_runtime.h>
#include <math.h>

#define N_NODES 100000
#define K_NBRS 16
#define N_EDGES (N_NODES * K_NBRS)
#define TPB 256
#define NBLK 2048

typedef __attribute__((ext_vector_type(8))) short short8;   // bf16x8 MFMA frag
typedef __attribute__((ext_vector_type(4))) float float4_;  // MFMA C/D frag
typedef __attribute__((ext_vector_type(4))) int int4_;
typedef __attribute__((ext_vector_type(4))) unsigned short ushort4_;

// RNE float->bf16 (bits) and back
__device__ __forceinline__ unsigned short f2bf(float f) {
  unsigned int u = __float_as_uint(f);
  u += 0x7fffu + ((u >> 16) & 1u);
  return (unsigned short)(u >> 16);
}
__device__ __forceinline__ float bf2f(unsigned short b) {
  return __uint_as_float(((unsigned int)b) << 16);
}

// Merged: (1) normalize edge_index row0 to int32; (2) layer-1 node GEMM
// A = x @ (W1_top - W1_bot) + b1 ; B = x @ W1_bot. Both bf16 tables now.
__global__ void k_pre(const int* __restrict__ ei, int* __restrict__ srcout,
                      const float* __restrict__ x, const float* __restrict__ W1,
                      const float* __restrict__ b1,
                      unsigned short* __restrict__ A, unsigned short* __restrict__ B) {
  const bool is64 = (ei[1] == 0) && (ei[3] == 0) && (ei[5] == 0) && (ei[7] == 0);
  const int tid = blockIdx.x * blockDim.x + threadIdx.x;
  const int stride = gridDim.x * blockDim.x;
  for (int e = tid; e < N_EDGES; e += stride)
    srcout[e] = is64 ? ei[2 * e] : ei[e];

  const int lane = threadIdx.x & 63;
  const int nwaves = stride >> 6;
  const int wid0 = tid >> 6;
  float w[6];
#pragma unroll
  for (int k = 0; k < 6; ++k) w[k] = W1[k * 64 + lane];
  const float bias = b1[lane];
  for (int i0 = wid0; i0 < N_NODES; i0 += nwaves) {
    const int i = __builtin_amdgcn_readfirstlane(i0);
    const float x0 = x[3 * i], x1 = x[3 * i + 1], x2 = x[3 * i + 2];
    const float b = fmaf(x0, w[3], fmaf(x1, w[4], x2 * w[5]));
    const float a = bias + fmaf(x0, w[0] - w[3],
                          fmaf(x1, w[1] - w[4], x2 * (w[2] - w[5])));
    A[(size_t)i * 64 + lane] = f2bf(a);
    B[(size_t)i * 64 + lane] = f2bf(b);
  }
}

// Gather + max aggregation: h[i] = relu(A[i] + max_e B[src[i*16+e]]).
// Quarter q owns rows 4q..4q+3; (lane&15) owns 4 channels; dwordx2 gathers.
// Software-pipelined: next group's idx + A-row prefetched during gathers.
template <bool DO_GMAX>
__global__ void k_aggr(const int* __restrict__ src,
                       const unsigned short* __restrict__ Ain,
                       const unsigned short* __restrict__ Bin,
                       unsigned short* __restrict__ hout, float* __restrict__ P) {
  const int lane = threadIdx.x & 63;
  const int q = lane >> 4;
  const int c4 = (lane & 15) * 4;
  const int nw = (gridDim.x * blockDim.x) >> 6;
  const int w0 = (blockIdx.x * blockDim.x + threadIdx.x) >> 6;
  float4_ gmax = (float4_)(0.f);
  int p = w0;
  int4_ idx[4];
  ushort4_ avp;
  if (p * 4 < N_NODES) {
    const int i0 = __builtin_amdgcn_readfirstlane(p * 4);
#pragma unroll
    for (int n = 0; n < 4; ++n)
      idx[n] = *(const int4_*)(src + (size_t)(i0 + n) * 16 + q * 4);
    avp = *(const ushort4_*)(Ain + (size_t)(i0 + q) * 64 + c4);
  }
  while (p * 4 < N_NODES) {
    const int i0 = __builtin_amdgcn_readfirstlane(p * 4);
    ushort4_ gv[4][4];
#pragma unroll
    for (int n = 0; n < 4; ++n)
#pragma unroll
      for (int e = 0; e < 4; ++e)
        gv[n][e] = *(const ushort4_*)(Bin + (size_t)idx[n][e] * 64 + c4);
    const int pn = p + nw;          // prefetch next group under the gathers
    int4_ idxn[4];
    ushort4_ avn;
    if (pn * 4 < N_NODES) {
      const int i1 = __builtin_amdgcn_readfirstlane(pn * 4);
#pragma unroll
      for (int n = 0; n < 4; ++n)
        idxn[n] = *(const int4_*)(src + (size_t)(i1 + n) * 16 + q * 4);
      avn = *(const ushort4_*)(Ain + (size_t)(i1 + q) * 64 + c4);
    }
    float4_ m[4];
#pragma unroll
    for (int n = 0; n < 4; ++n) {
#pragma unroll
      for (int t = 0; t < 4; ++t) {
        const float v0 = bf2f(gv[n][0][t]), v1 = bf2f(gv[n][1][t]);
        const float v2 = bf2f(gv[n][2][t]), v3 = bf2f(gv[n][3][t]);
        m[n][t] = fmaxf(fmaxf(v0, v1), fmaxf(v2, v3));
      }
#pragma unroll
      for (int t = 0; t < 4; ++t) {  // cross-quarter (rows) reduce
        float v = m[n][t];
        v = fmaxf(v, __shfl_xor(v, 16));
        v = fmaxf(v, __shfl_xor(v, 32));
        m[n][t] = v;
      }
    }
    ushort4_ hb;
#pragma unroll
    for (int t = 0; t < 4; ++t) {    // select m[q] (static chain)
      float v = m[0][t];
      v = (q == 1) ? m[1][t] : v;
      v = (q == 2) ? m[2][t] : v;
      v = (q == 3) ? m[3][t] : v;
      const float h = fmaxf(bf2f(avp[t]) + v, 0.f);
      hb[t] = f2bf(h);
      if constexpr (DO_GMAX) gmax[t] = fmaxf(gmax[t], h);
    }
    *(ushort4_*)(hout + (size_t)(i0 + q) * 64 + c4) = hb;
    p = pn;
#pragma unroll
    for (int n = 0; n < 4; ++n) idx[n] = idxn[n];
    avp = avn;
  }
  if constexpr (DO_GMAX) {
    __shared__ float red[TPB][4];
#pragma unroll
    for (int t = 0; t < 4; ++t) red[threadIdx.x][t] = gmax[t];
    __syncthreads();
    if (threadIdx.x < 64) {
      const int c = threadIdx.x, j = c >> 2, t = c & 3;
      float mm = 0.f;
#pragma unroll
      for (int w = 0; w < 4; ++w)
#pragma unroll
        for (int qq = 0; qq < 4; ++qq)
          mm = fmaxf(mm, red[w * 64 + qq * 16 + j][t]);
      P[(size_t)blockIdx.x * 64 + c] = mm;
    }
  }
}

// MFMA node-GEMM: [Aout|Bout] = h @ [Wtop-Wbot | Wbot] (+bias on A).
// h bf16 (direct A-frag); weights split hi+lo; outputs both bf16 now.
__global__ __launch_bounds__(TPB, 2)
void k_gemm(const unsigned short* __restrict__ h, const float* __restrict__ W,
            const float* __restrict__ bn,
            unsigned short* __restrict__ Aout, unsigned short* __restrict__ Bout) {
  __shared__ unsigned short lwhi[128 * 72];  // W'^T [j][k], stride 72
  __shared__ unsigned short lwlo[128 * 72];
  for (int idx = threadIdx.x; idx < 8192; idx += TPB) {
    const int k = idx >> 7, j = idx & 127;
    const float v = (j < 64) ? (W[k * 64 + j] - W[(64 + k) * 64 + j])
                             : W[(64 + k) * 64 + (j - 64)];
    const unsigned short hi = f2bf(v);
    lwhi[j * 72 + k] = hi;
    lwlo[j * 72 + k] = f2bf(v - bf2f(hi));
  }
  __syncthreads();
  const int lane = threadIdx.x & 63;
  const int wav = threadIdx.x >> 6;
  const int l15 = lane & 15, lg = lane >> 4;
  short8 bhi[8][2], blo[8][2];
#pragma unroll
  for (int ct = 0; ct < 8; ++ct)
#pragma unroll
    for (int kk = 0; kk < 2; ++kk) {
      const int off = (ct * 16 + l15) * 72 + kk * 32 + lg * 8;
      bhi[ct][kk] = *(const short8*)&lwhi[off];
      blo[ct][kk] = *(const short8*)&lwlo[off];
    }
  float bv[4];
#pragma unroll
  for (int ct = 0; ct < 4; ++ct) bv[ct] = bn[ct * 16 + l15];
  const int NT = (N_NODES + 63) / 64;
  for (int t = blockIdx.x; t < NT; t += gridDim.x) {
    const int nb = t * 64 + wav * 16;
    const int row = min(nb + l15, N_NODES - 1);
    const unsigned short* hr = h + (size_t)row * 64;
    float4_ acc[8];
#pragma unroll
    for (int ct = 0; ct < 8; ++ct) acc[ct] = (float4_)(0.f);
#pragma unroll
    for (int kk = 0; kk < 2; ++kk) {
      const short8 ahi = *(const short8*)(hr + kk * 32 + lg * 8);
#pragma unroll
      for (int ct = 0; ct < 8; ++ct) {
        acc[ct] = __builtin_amdgcn_mfma_f32_16x16x32_bf16(ahi, bhi[ct][kk], acc[ct], 0, 0, 0);
        acc[ct] = __builtin_amdgcn_mfma_f32_16x16x32_bf16(ahi, blo[ct][kk], acc[ct], 0, 0, 0);
      }
    }
#pragma unroll
    for (int ct = 0; ct < 8; ++ct)
#pragma unroll
      for (int r = 0; r < 4; ++r) {
        const int node = nb + lg * 4 + r;
        if (node < N_NODES) {
          if (ct < 4)
            Aout[(size_t)node * 64 + ct * 16 + l15] = f2bf(acc[ct][r] + bv[ct]);
          else
            Bout[(size_t)node * 64 + (ct - 4) * 16 + l15] = f2bf(acc[ct][r]);
        }
      }
  }
}

// Tree-reduce 2048 per-block partials to g[64].
__global__ void k_gred(const float* __restrict__ P, float* __restrict__ g) {
  __shared__ float red[16][64];
  const int lane = threadIdx.x & 63;
  const int w = threadIdx.x >> 6;
  float m = 0.f;
  for (int r = w; r < NBLK; r += 16)
    m = fmaxf(m, P[(size_t)r * 64 + lane]);
  red[w][lane] = m;
  __syncthreads();
  if (threadIdx.x < 64) {
    float mm = 0.f;
#pragma unroll
    for (int k = 0; k < 16; ++k) mm = fmaxf(mm, red[k][lane]);
    g[lane] = mm;
  }
}

// Head: hidden = relu(h @ Wa_top + gt), gt = ba + g @ Wa_bot;
// out = x + hidden @ Wb + bb.
__global__ __launch_bounds__(TPB, 2)
void k_final(const unsigned short* __restrict__ h, const float* __restrict__ g,
             const float* __restrict__ Wa, const float* __restrict__ ba,
             const float* __restrict__ Wb, const float* __restrict__ bb,
             const float* __restrict__ x, float* __restrict__ out) {
  __shared__ unsigned short lwhi[128 * 72];
  __shared__ unsigned short lwlo[128 * 72];
  __shared__ float sgt[128];
  for (int idx = threadIdx.x; idx < 8192; idx += TPB) {
    const int k = idx >> 7, j = idx & 127;
    const float v = Wa[k * 128 + j];
    const unsigned short hi = f2bf(v);
    lwhi[j * 72 + k] = hi;
    lwlo[j * 72 + k] = f2bf(v - bf2f(hi));
  }
  if (threadIdx.x < 128) {
    const int c = threadIdx.x;
    float s = ba[c];
    for (int k = 0; k < 64; ++k) s = fmaf(g[k], Wa[(64 + k) * 128 + c], s);
    sgt[c] = s;
  }
  __syncthreads();
  const int lane = threadIdx.x & 63;
  const int wav = threadIdx.x >> 6;
  const int l15 = lane & 15, lg = lane >> 4;
  short8 bhi[8][2], blo[8][2];
#pragma unroll
  for (int ct = 0; ct < 8; ++ct)
#pragma unroll
    for (int kk = 0; kk < 2; ++kk) {
      const int off = (ct * 16 + l15) * 72 + kk * 32 + lg * 8;
      bhi[ct][kk] = *(const short8*)&lwhi[off];
      blo[ct][kk] = *(const short8*)&lwlo[off];
    }
  float gtv[8];
#pragma unroll
  for (int ct = 0; ct < 8; ++ct) gtv[ct] = sgt[ct * 16 + l15];
  float wbv[8][3];
#pragma unroll
  for (int ct = 0; ct < 8; ++ct)
#pragma unroll
    for (int jj = 0; jj < 3; ++jj)
      wbv[ct][jj] = Wb[(ct * 16 + l15) * 3 + jj];
  const float bbl = (l15 == 0) ? bb[0] : (l15 == 1 ? bb[1] : bb[2]);
  const int NT = (N_NODES + 63) / 64;
  for (int t = blockIdx.x; t < NT; t += gridDim.x) {
    const int nb = t * 64 + wav * 16;
    const int row = min(nb + l15, N_NODES - 1);
    const unsigned short* hr = h + (size_t)row * 64;
    float4_ acc[8];
#pragma unroll
    for (int ct = 0; ct < 8; ++ct) acc[ct] = (float4_)(0.f);
#pragma unroll
    for (int kk = 0; kk < 2; ++kk) {
      const short8 ahi = *(const short8*)(hr + kk * 32 + lg * 8);
#pragma unroll
      for (int ct = 0; ct < 8; ++ct) {
        acc[ct] = __builtin_amdgcn_mfma_f32_16x16x32_bf16(ahi, bhi[ct][kk], acc[ct], 0, 0, 0);
        acc[ct] = __builtin_amdgcn_mfma_f32_16x16x32_bf16(ahi, blo[ct][kk], acc[ct], 0, 0, 0);
      }
    }
#pragma unroll
    for (int r = 0; r < 4; ++r) {
      float t0 = 0.f, t1 = 0.f, t2 = 0.f;
#pragma unroll
      for (int ct = 0; ct < 8; ++ct) {
        const float hd = fmaxf(acc[ct][r] + gtv[ct], 0.f);
        t0 = fmaf(hd, wbv[ct][0], t0);
        t1 = fmaf(hd, wbv[ct][1], t1);
        t2 = fmaf(hd, wbv[ct][2], t2);
      }
#pragma unroll
      for (int off = 1; off < 16; off <<= 1) {
        t0 += __shfl_xor(t0, off);
        t1 += __shfl_xor(t1, off);
        t2 += __shfl_xor(t2, off);
      }
      const int node = nb + lg * 4 + r;
      if (node < N_NODES && l15 < 3) {
        const float tj = (l15 == 0) ? t0 : (l15 == 1 ? t1 : t2);
        out[(size_t)node * 3 + l15] = x[(size_t)node * 3 + l15] + tj + bbl;
      }
    }
  }
}

extern "C" void kernel_launch(void* const* d_in, const int* in_sizes, int n_in,
                              void* d_out, int out_size, void* d_ws, size_t ws_size,
                              hipStream_t stream) {
  const float* x  = (const float*)d_in[0];
  const int*   ei = (const int*)d_in[1];
  const float* W1 = (const float*)d_in[2];
  const float* b1 = (const float*)d_in[3];
  const float* W2 = (const float*)d_in[4];
  const float* b2 = (const float*)d_in[5];
  const float* W3 = (const float*)d_in[6];
  const float* b3 = (const float*)d_in[7];
  const float* W4 = (const float*)d_in[8];
  const float* b4 = (const float*)d_in[9];
  const float* W5 = (const float*)d_in[10];
  const float* b5 = (const float*)d_in[11];
  const float* Wa = (const float*)d_in[12];
  const float* ba = (const float*)d_in[13];
  const float* Wb = (const float*)d_in[14];
  const float* bb = (const float*)d_in[15];
  float* out = (float*)d_out;

  // ws layout: src[1.6M int] | A0,A1,H,B0,B1 [6.4M ushort each] | P | g
  float* ws = (float*)d_ws;
  int* srcbuf = (int*)ws;
  unsigned short* A0 = (unsigned short*)(ws + 1600000);
  unsigned short* A1 = A0 + 6400000;
  unsigned short* H  = A1 + 6400000;
  unsigned short* B0 = H + 6400000;
  unsigned short* B1 = B0 + 6400000;
  float* P = (float*)(B1 + 6400000);
  float* g = P + (size_t)NBLK * 64;

  k_pre<<<NBLK, TPB, 0, stream>>>(ei, srcbuf, x, W1, b1, A0, B0);
  k_aggr<false><<<NBLK, TPB, 0, stream>>>(srcbuf, A0, B0, H, nullptr);
  k_gemm<<<1024, TPB, 0, stream>>>(H, W2, b2, A1, B1);
  k_aggr<false><<<NBLK, TPB, 0, stream>>>(srcbuf, A1, B1, H, nullptr);
  k_gemm<<<1024, TPB, 0, stream>>>(H, W3, b3, A0, B0);
  k_aggr<false><<<NBLK, TPB, 0, stream>>>(srcbuf, A0, B0, H, nullptr);
  k_gemm<<<1024, TPB, 0, stream>>>(H, W4, b4, A1, B1);
  k_aggr<false><<<NBLK, TPB, 0, stream>>>(srcbuf, A1, B1, H, nullptr);
  k_gemm<<<1024, TPB, 0, stream>>>(H, W5, b5, A0, B0);
  k_aggr<true><<<NBLK, TPB, 0, stream>>>(srcbuf, A0, B0, H, P);
  k_gred<<<1, 1024, 0, stream>>>(P, g);
  k_final<<<1024, TPB, 0, stream>>>(H, g, Wa, ba, Wb, bb, x, out);
}

// Round 7
// 374.557 us; speedup vs baseline: 1.0685x; 1.0685x over previous
//
#include <hip/hip_runtime.h>
#include <math.h>

#define N_NODES 100000
#define K_NBRS 16
#define N_EDGES (N_NODES * K_NBRS)
#define TPB 256
#define NBLK 2048
#define NTILES (N_NODES / 16)  // 6250 exact

typedef __attribute__((ext_vector_type(8))) short short8;   // bf16x8 MFMA frag
typedef __attribute__((ext_vector_type(4))) float float4_;  // MFMA C/D frag
typedef __attribute__((ext_vector_type(4))) int int4_;
typedef __attribute__((ext_vector_type(4))) unsigned short ushort4_;

// RNE float->bf16 (bits) and back
__device__ __forceinline__ unsigned short f2bf(float f) {
  unsigned int u = __float_as_uint(f);
  u += 0x7fffu + ((u >> 16) & 1u);
  return (unsigned short)(u >> 16);
}
__device__ __forceinline__ float bf2f(unsigned short b) {
  return __uint_as_float(((unsigned int)b) << 16);
}

// Merged: (1) normalize edge_index row0 to int32; (2) layer-1 node GEMM
// A = x @ (W1_top - W1_bot) + b1 ; B = x @ W1_bot. Both bf16 tables.
__global__ void k_pre(const int* __restrict__ ei, int* __restrict__ srcout,
                      const float* __restrict__ x, const float* __restrict__ W1,
                      const float* __restrict__ b1,
                      unsigned short* __restrict__ A, unsigned short* __restrict__ B) {
  const bool is64 = (ei[1] == 0) && (ei[3] == 0) && (ei[5] == 0) && (ei[7] == 0);
  const int tid = blockIdx.x * blockDim.x + threadIdx.x;
  const int stride = gridDim.x * blockDim.x;
  for (int e = tid; e < N_EDGES; e += stride)
    srcout[e] = is64 ? ei[2 * e] : ei[e];

  const int lane = threadIdx.x & 63;
  const int nwaves = stride >> 6;
  const int wid0 = tid >> 6;
  float w[6];
#pragma unroll
  for (int k = 0; k < 6; ++k) w[k] = W1[k * 64 + lane];
  const float bias = b1[lane];
  for (int i0 = wid0; i0 < N_NODES; i0 += nwaves) {
    const int i = __builtin_amdgcn_readfirstlane(i0);
    const float x0 = x[3 * i], x1 = x[3 * i + 1], x2 = x[3 * i + 2];
    const float b = fmaf(x0, w[3], fmaf(x1, w[4], x2 * w[5]));
    const float a = bias + fmaf(x0, w[0] - w[3],
                          fmaf(x1, w[1] - w[4], x2 * (w[2] - w[5])));
    A[(size_t)i * 64 + lane] = f2bf(a);
    B[(size_t)i * 64 + lane] = f2bf(b);
  }
}

// FUSED layer: per 16-node tile: (a) gather+max aggregation (4 waves x 4 nodes,
// quarter q owns rows 4q..4q+3 then node's A-add), h -> LDS (stride-72 pad);
// (b) MFMA node-GEMM [Aout|Bout] = h @ [Wtop-Wbot | Wbot] (+bias), wave w
// computing column-tiles {2w, 2w+1}. Weights (hi+lo split) in LDS per block.
__global__ __launch_bounds__(TPB, 4)
void k_fused(const int* __restrict__ src,
             const unsigned short* __restrict__ Ain,
             const unsigned short* __restrict__ Bin,
             const float* __restrict__ W, const float* __restrict__ bn,
             unsigned short* __restrict__ Aout, unsigned short* __restrict__ Bout) {
  __shared__ __align__(16) unsigned short lwhi[128 * 72];  // W'^T [j][k]
  __shared__ __align__(16) unsigned short lwlo[128 * 72];
  __shared__ __align__(16) unsigned short lh[16 * 72];     // h tile, padded rows
  for (int idx = threadIdx.x; idx < 8192; idx += TPB) {
    const int k = idx >> 7, j = idx & 127;
    const float v = (j < 64) ? (W[k * 64 + j] - W[(64 + k) * 64 + j])
                             : W[(64 + k) * 64 + (j - 64)];
    const unsigned short hi = f2bf(v);
    lwhi[j * 72 + k] = hi;
    lwlo[j * 72 + k] = f2bf(v - bf2f(hi));
  }
  const int lane = threadIdx.x & 63;
  const int wav = threadIdx.x >> 6;
  const int q = lane >> 4;         // quarter (also MFMA lg)
  const int l15 = lane & 15;
  const int c4 = l15 * 4;
  float bv0 = 0.f, bv1 = 0.f;      // bias, only waves 0/1 (A-half tiles)
  if (wav < 2) {
    bv0 = bn[(2 * wav) * 16 + l15];
    bv1 = bn[(2 * wav + 1) * 16 + l15];
  }
  __syncthreads();
  for (int t = blockIdx.x; t < NTILES; t += gridDim.x) {
    // ---- aggregation: nodes i0..i0+3 for this wave ----
    const int i0 = t * 16 + wav * 4;
    int4_ idx[4];
#pragma unroll
    for (int n = 0; n < 4; ++n)
      idx[n] = *(const int4_*)(src + (size_t)(i0 + n) * 16 + q * 4);
    ushort4_ gv[4][4];
#pragma unroll
    for (int n = 0; n < 4; ++n)
#pragma unroll
      for (int e = 0; e < 4; ++e)
        gv[n][e] = *(const ushort4_*)(Bin + (size_t)idx[n][e] * 64 + c4);
    const ushort4_ av = *(const ushort4_*)(Ain + (size_t)(i0 + q) * 64 + c4);
    float4_ m[4];
#pragma unroll
    for (int n = 0; n < 4; ++n) {
#pragma unroll
      for (int tt = 0; tt < 4; ++tt) {
        const float v0 = bf2f(gv[n][0][tt]), v1 = bf2f(gv[n][1][tt]);
        const float v2 = bf2f(gv[n][2][tt]), v3 = bf2f(gv[n][3][tt]);
        m[n][tt] = fmaxf(fmaxf(v0, v1), fmaxf(v2, v3));
      }
#pragma unroll
      for (int tt = 0; tt < 4; ++tt) {  // cross-quarter reduce (rows)
        float v = m[n][tt];
        v = fmaxf(v, __shfl_xor(v, 16));
        v = fmaxf(v, __shfl_xor(v, 32));
        m[n][tt] = v;
      }
    }
    ushort4_ hb;
#pragma unroll
    for (int tt = 0; tt < 4; ++tt) {    // select m[q] (static chain)
      float v = m[0][tt];
      v = (q == 1) ? m[1][tt] : v;
      v = (q == 2) ? m[2][tt] : v;
      v = (q == 3) ? m[3][tt] : v;
      hb[tt] = f2bf(fmaxf(bf2f(av[tt]) + v, 0.f));
    }
    *(ushort4_*)&lh[(wav * 4 + q) * 72 + c4] = hb;
    __syncthreads();
    // ---- MFMA: this wave does column-tiles ct = 2*wav, 2*wav+1 ----
    const short8 a0 = *(const short8*)&lh[l15 * 72 + q * 8];
    const short8 a1 = *(const short8*)&lh[l15 * 72 + 32 + q * 8];
    float4_ acc0 = (float4_)(0.f), acc1 = (float4_)(0.f);
    {
      const int ct0 = wav * 2, ct1 = wav * 2 + 1;
      const int r0 = (ct0 * 16 + l15) * 72 + q * 8;
      const int r1 = (ct1 * 16 + l15) * 72 + q * 8;
      acc0 = __builtin_amdgcn_mfma_f32_16x16x32_bf16(a0, *(const short8*)&lwhi[r0], acc0, 0, 0, 0);
      acc0 = __builtin_amdgcn_mfma_f32_16x16x32_bf16(a0, *(const short8*)&lwlo[r0], acc0, 0, 0, 0);
      acc0 = __builtin_amdgcn_mfma_f32_16x16x32_bf16(a1, *(const short8*)&lwhi[r0 + 32], acc0, 0, 0, 0);
      acc0 = __builtin_amdgcn_mfma_f32_16x16x32_bf16(a1, *(const short8*)&lwlo[r0 + 32], acc0, 0, 0, 0);
      acc1 = __builtin_amdgcn_mfma_f32_16x16x32_bf16(a0, *(const short8*)&lwhi[r1], acc1, 0, 0, 0);
      acc1 = __builtin_amdgcn_mfma_f32_16x16x32_bf16(a0, *(const short8*)&lwlo[r1], acc1, 0, 0, 0);
      acc1 = __builtin_amdgcn_mfma_f32_16x16x32_bf16(a1, *(const short8*)&lwhi[r1 + 32], acc1, 0, 0, 0);
      acc1 = __builtin_amdgcn_mfma_f32_16x16x32_bf16(a1, *(const short8*)&lwlo[r1 + 32], acc1, 0, 0, 0);
    }
#pragma unroll
    for (int r = 0; r < 4; ++r) {
      const int node = t * 16 + q * 4 + r;   // C/D row = q*4 + reg
      const int ct0 = wav * 2, ct1 = wav * 2 + 1;
      if (wav < 2) {  // A-half with bias
        Aout[(size_t)node * 64 + ct0 * 16 + l15] = f2bf(acc0[r] + bv0);
        Aout[(size_t)node * 64 + ct1 * 16 + l15] = f2bf(acc1[r] + bv1);
      } else {        // B-half
        Bout[(size_t)node * 64 + (ct0 - 4) * 16 + l15] = f2bf(acc0[r]);
        Bout[(size_t)node * 64 + (ct1 - 4) * 16 + l15] = f2bf(acc1[r]);
      }
    }
    __syncthreads();  // lh reuse fence for next tile
  }
}

// Last layer: aggregation only (no pipelining), writes h + per-block gmax partials.
__global__ void k_aggr_last(const int* __restrict__ src,
                            const unsigned short* __restrict__ Ain,
                            const unsigned short* __restrict__ Bin,
                            unsigned short* __restrict__ hout, float* __restrict__ P) {
  const int lane = threadIdx.x & 63;
  const int q = lane >> 4;
  const int c4 = (lane & 15) * 4;
  const int nw = (gridDim.x * blockDim.x) >> 6;
  const int w0 = (blockIdx.x * blockDim.x + threadIdx.x) >> 6;
  float4_ gmax = (float4_)(0.f);
  for (int p = w0; p * 4 < N_NODES; p += nw) {
    const int i0 = __builtin_amdgcn_readfirstlane(p * 4);
    int4_ idx[4];
#pragma unroll
    for (int n = 0; n < 4; ++n)
      idx[n] = *(const int4_*)(src + (size_t)(i0 + n) * 16 + q * 4);
    ushort4_ gv[4][4];
#pragma unroll
    for (int n = 0; n < 4; ++n)
#pragma unroll
      for (int e = 0; e < 4; ++e)
        gv[n][e] = *(const ushort4_*)(Bin + (size_t)idx[n][e] * 64 + c4);
    const ushort4_ av = *(const ushort4_*)(Ain + (size_t)(i0 + q) * 64 + c4);
    float4_ m[4];
#pragma unroll
    for (int n = 0; n < 4; ++n) {
#pragma unroll
      for (int tt = 0; tt < 4; ++tt) {
        const float v0 = bf2f(gv[n][0][tt]), v1 = bf2f(gv[n][1][tt]);
        const float v2 = bf2f(gv[n][2][tt]), v3 = bf2f(gv[n][3][tt]);
        m[n][tt] = fmaxf(fmaxf(v0, v1), fmaxf(v2, v3));
      }
#pragma unroll
      for (int tt = 0; tt < 4; ++tt) {
        float v = m[n][tt];
        v = fmaxf(v, __shfl_xor(v, 16));
        v = fmaxf(v, __shfl_xor(v, 32));
        m[n][tt] = v;
      }
    }
    ushort4_ hb;
#pragma unroll
    for (int tt = 0; tt < 4; ++tt) {
      float v = m[0][tt];
      v = (q == 1) ? m[1][tt] : v;
      v = (q == 2) ? m[2][tt] : v;
      v = (q == 3) ? m[3][tt] : v;
      const float h = fmaxf(bf2f(av[tt]) + v, 0.f);
      hb[tt] = f2bf(h);
      gmax[tt] = fmaxf(gmax[tt], h);
    }
    *(ushort4_*)(hout + (size_t)(i0 + q) * 64 + c4) = hb;
  }
  __shared__ float red[TPB][4];
#pragma unroll
  for (int tt = 0; tt < 4; ++tt) red[threadIdx.x][tt] = gmax[tt];
  __syncthreads();
  if (threadIdx.x < 64) {
    const int c = threadIdx.x, j = c >> 2, tt = c & 3;
    float mm = 0.f;
#pragma unroll
    for (int w = 0; w < 4; ++w)
#pragma unroll
      for (int qq = 0; qq < 4; ++qq)
        mm = fmaxf(mm, red[w * 64 + qq * 16 + j][tt]);
    P[(size_t)blockIdx.x * 64 + c] = mm;
  }
}

// Tree-reduce 2048 per-block partials to g[64].
__global__ void k_gred(const float* __restrict__ P, float* __restrict__ g) {
  __shared__ float red[16][64];
  const int lane = threadIdx.x & 63;
  const int w = threadIdx.x >> 6;
  float m = 0.f;
  for (int r = w; r < NBLK; r += 16)
    m = fmaxf(m, P[(size_t)r * 64 + lane]);
  red[w][lane] = m;
  __syncthreads();
  if (threadIdx.x < 64) {
    float mm = 0.f;
#pragma unroll
    for (int k = 0; k < 16; ++k) mm = fmaxf(mm, red[k][lane]);
    g[lane] = mm;
  }
}

// Head: hidden = relu(h @ Wa_top + gt), gt = ba + g @ Wa_bot;
// out = x + hidden @ Wb + bb.
__global__ __launch_bounds__(TPB, 2)
void k_final(const unsigned short* __restrict__ h, const float* __restrict__ g,
             const float* __restrict__ Wa, const float* __restrict__ ba,
             const float* __restrict__ Wb, const float* __restrict__ bb,
             const float* __restrict__ x, float* __restrict__ out) {
  __shared__ __align__(16) unsigned short lwhi[128 * 72];
  __shared__ __align__(16) unsigned short lwlo[128 * 72];
  __shared__ float sgt[128];
  for (int idx = threadIdx.x; idx < 8192; idx += TPB) {
    const int k = idx >> 7, j = idx & 127;
    const float v = Wa[k * 128 + j];
    const unsigned short hi = f2bf(v);
    lwhi[j * 72 + k] = hi;
    lwlo[j * 72 + k] = f2bf(v - bf2f(hi));
  }
  if (threadIdx.x < 128) {
    const int c = threadIdx.x;
    float s = ba[c];
    for (int k = 0; k < 64; ++k) s = fmaf(g[k], Wa[(64 + k) * 128 + c], s);
    sgt[c] = s;
  }
  __syncthreads();
  const int lane = threadIdx.x & 63;
  const int wav = threadIdx.x >> 6;
  const int l15 = lane & 15, lg = lane >> 4;
  short8 bhi[8][2], blo[8][2];
#pragma unroll
  for (int ct = 0; ct < 8; ++ct)
#pragma unroll
    for (int kk = 0; kk < 2; ++kk) {
      const int off = (ct * 16 + l15) * 72 + kk * 32 + lg * 8;
      bhi[ct][kk] = *(const short8*)&lwhi[off];
      blo[ct][kk] = *(const short8*)&lwlo[off];
    }
  float gtv[8];
#pragma unroll
  for (int ct = 0; ct < 8; ++ct) gtv[ct] = sgt[ct * 16 + l15];
  float wbv[8][3];
#pragma unroll
  for (int ct = 0; ct < 8; ++ct)
#pragma unroll
    for (int jj = 0; jj < 3; ++jj)
      wbv[ct][jj] = Wb[(ct * 16 + l15) * 3 + jj];
  const float bbl = (l15 == 0) ? bb[0] : (l15 == 1 ? bb[1] : bb[2]);
  const int NT = (N_NODES + 63) / 64;
  for (int t = blockIdx.x; t < NT; t += gridDim.x) {
    const int nb = t * 64 + wav * 16;
    const int row = min(nb + l15, N_NODES - 1);
    const unsigned short* hr = h + (size_t)row * 64;
    float4_ acc[8];
#pragma unroll
    for (int ct = 0; ct < 8; ++ct) acc[ct] = (float4_)(0.f);
#pragma unroll
    for (int kk = 0; kk < 2; ++kk) {
      const short8 ahi = *(const short8*)(hr + kk * 32 + lg * 8);
#pragma unroll
      for (int ct = 0; ct < 8; ++ct) {
        acc[ct] = __builtin_amdgcn_mfma_f32_16x16x32_bf16(ahi, bhi[ct][kk], acc[ct], 0, 0, 0);
        acc[ct] = __builtin_amdgcn_mfma_f32_16x16x32_bf16(ahi, blo[ct][kk], acc[ct], 0, 0, 0);
      }
    }
#pragma unroll
    for (int r = 0; r < 4; ++r) {
      float t0 = 0.f, t1 = 0.f, t2 = 0.f;
#pragma unroll
      for (int ct = 0; ct < 8; ++ct) {
        const float hd = fmaxf(acc[ct][r] + gtv[ct], 0.f);
        t0 = fmaf(hd, wbv[ct][0], t0);
        t1 = fmaf(hd, wbv[ct][1], t1);
        t2 = fmaf(hd, wbv[ct][2], t2);
      }
#pragma unroll
      for (int off = 1; off < 16; off <<= 1) {
        t0 += __shfl_xor(t0, off);
        t1 += __shfl_xor(t1, off);
        t2 += __shfl_xor(t2, off);
      }
      const int node = nb + lg * 4 + r;
      if (node < N_NODES && l15 < 3) {
        const float tj = (l15 == 0) ? t0 : (l15 == 1 ? t1 : t2);
        out[(size_t)node * 3 + l15] = x[(size_t)node * 3 + l15] + tj + bbl;
      }
    }
  }
}

extern "C" void kernel_launch(void* const* d_in, const int* in_sizes, int n_in,
                              void* d_out, int out_size, void* d_ws, size_t ws_size,
                              hipStream_t stream) {
  const float* x  = (const float*)d_in[0];
  const int*   ei = (const int*)d_in[1];
  const float* W1 = (const float*)d_in[2];
  const float* b1 = (const float*)d_in[3];
  const float* W2 = (const float*)d_in[4];
  const float* b2 = (const float*)d_in[5];
  const float* W3 = (const float*)d_in[6];
  const float* b3 = (const float*)d_in[7];
  const float* W4 = (const float*)d_in[8];
  const float* b4 = (const float*)d_in[9];
  const float* W5 = (const float*)d_in[10];
  const float* b5 = (const float*)d_in[11];
  const float* Wa = (const float*)d_in[12];
  const float* ba = (const float*)d_in[13];
  const float* Wb = (const float*)d_in[14];
  const float* bb = (const float*)d_in[15];
  float* out = (float*)d_out;

  // ws layout: src[1.6M int] | A0,B0,A1,B1,H [6.4M ushort each] | P | g
  float* ws = (float*)d_ws;
  int* srcbuf = (int*)ws;
  unsigned short* A0 = (unsigned short*)(ws + 1600000);
  unsigned short* B0 = A0 + 6400000;
  unsigned short* A1 = B0 + 6400000;
  unsigned short* B1 = A1 + 6400000;
  unsigned short* H  = B1 + 6400000;
  float* P = (float*)(H + 6400000);
  float* g = P + (size_t)NBLK * 64;

  k_pre<<<NBLK, TPB, 0, stream>>>(ei, srcbuf, x, W1, b1, A0, B0);
  k_fused<<<NBLK, TPB, 0, stream>>>(srcbuf, A0, B0, W2, b2, A1, B1);
  k_fused<<<NBLK, TPB, 0, stream>>>(srcbuf, A1, B1, W3, b3, A0, B0);
  k_fused<<<NBLK, TPB, 0, stream>>>(srcbuf, A0, B0, W4, b4, A1, B1);
  k_fused<<<NBLK, TPB, 0, stream>>>(srcbuf, A1, B1, W5, b5, A0, B0);
  k_aggr_last<<<NBLK, TPB, 0, stream>>>(srcbuf, A0, B0, H, P);
  k_gred<<<1, 1024, 0, stream>>>(P, g);
  k_final<<<512, TPB, 0, stream>>>(H, g, Wa, ba, Wb, bb, x, out);
}